// Round 1
// baseline (205.716 us; speedup 1.0000x reference)
//
#include <hip/hip_runtime.h>

typedef short bf16x8 __attribute__((ext_vector_type(8)));
typedef float f32x4 __attribute__((ext_vector_type(4)));

#define PITCH 72
#define NEG_INF (-__builtin_inff())

__device__ __forceinline__ unsigned short f2bf(float f) {
  union { float f; unsigned u; } v; v.f = f;
  return (unsigned short)((v.u + 0x7fffu + ((v.u >> 16) & 1u)) >> 16);
}

__device__ __forceinline__ f32x4 mfma16(bf16x8 a, bf16x8 b, f32x4 c) {
  return __builtin_amdgcn_mfma_f32_16x16x32_bf16(a, b, c, 0, 0, 0);
}

// ---------------- kernel 0: W -> W^T bf16 [192][384] ----------------
__global__ __launch_bounds__(256) void prep_w(const float* __restrict__ wq,
                                              const float* __restrict__ wk,
                                              const float* __restrict__ wv,
                                              unsigned short* __restrict__ wt) {
  int i = blockIdx.x * 256 + threadIdx.x;  // 0..24575 over [c][d] of one proj
  if (i >= 384 * 64) return;
  int c = i >> 6, d = i & 63;
  wt[(long)(0 * 64 + d) * 384 + c] = f2bf(wq[i]);
  wt[(long)(1 * 64 + d) * 384 + c] = f2bf(wk[i]);
  wt[(long)(2 * 64 + d) * 384 + c] = f2bf(wv[i]);
}

// ---------------- kernel 1: QKV projection ----------------
// grid 512 (64-token tiles), 256 threads. Outputs: q,k [tok][64] bf16; v^T [b][64][t] bf16.
__global__ __launch_bounds__(256) void proj_kernel(
    const float* __restrict__ x, const unsigned short* __restrict__ wt,
    unsigned short* __restrict__ qo, unsigned short* __restrict__ ko,
    unsigned short* __restrict__ vo) {
  __shared__ unsigned short xs[64][PITCH];    // [tok][c] (reused as v^T [d][tok] later)
  __shared__ unsigned short wsh[192][PITCH];  // [d][c]
  const int tid = threadIdx.x;
  const int lane = tid & 63, wave = tid >> 6;
  const int lo = lane & 15, quad = lane >> 4;
  const long tokbase = (long)blockIdx.x * 64;

  f32x4 acc[12];
#pragma unroll
  for (int nt = 0; nt < 12; ++nt) acc[nt] = (f32x4){0.f, 0.f, 0.f, 0.f};

  for (int c0 = 0; c0 < 384; c0 += 64) {
    // stage x tile (fp32 -> bf16)
#pragma unroll
    for (int it = 0; it < 4; ++it) {
      int tok = (tid >> 4) + it * 16;
      int cc = (tid & 15) * 4;
      float4 v = *(const float4*)(x + (tokbase + tok) * 384 + c0 + cc);
      ushort4 s;
      s.x = f2bf(v.x); s.y = f2bf(v.y); s.z = f2bf(v.z); s.w = f2bf(v.w);
      *(ushort4*)&xs[tok][cc] = s;
    }
    // stage W^T chunk (already bf16)
#pragma unroll
    for (int it = 0; it < 6; ++it) {
      int d = (tid >> 3) + it * 32;
      int cc = (tid & 7) * 8;
      float4 v = *(const float4*)(wt + (long)d * 384 + c0 + cc);
      *(float4*)&wsh[d][cc] = v;
    }
    __syncthreads();
    bf16x8 a0 = *(const bf16x8*)&xs[wave * 16 + lo][quad * 8];
    bf16x8 a1 = *(const bf16x8*)&xs[wave * 16 + lo][32 + quad * 8];
#pragma unroll
    for (int nt = 0; nt < 12; ++nt) {
      bf16x8 b0 = *(const bf16x8*)&wsh[nt * 16 + lo][quad * 8];
      bf16x8 b1 = *(const bf16x8*)&wsh[nt * 16 + lo][32 + quad * 8];
      acc[nt] = mfma16(a0, b0, acc[nt]);
      acc[nt] = mfma16(a1, b1, acc[nt]);
    }
    __syncthreads();
  }
  // epilogue: Q (nt 0..3), K (nt 4..7) straight stores
#pragma unroll
  for (int nt = 0; nt < 8; ++nt) {
    unsigned short* dst = (nt < 4) ? qo : ko;
    int d = (nt & 3) * 16 + lo;
#pragma unroll
    for (int r = 0; r < 4; ++r) {
      long t = tokbase + wave * 16 + quad * 4 + r;
      dst[t * 64 + d] = f2bf(acc[nt][r]);
    }
  }
  // V: transpose through LDS (reuse xs as [d][tok_local])
#pragma unroll
  for (int nt = 8; nt < 12; ++nt) {
    int d = (nt - 8) * 16 + lo;
#pragma unroll
    for (int r = 0; r < 4; ++r) {
      int tl = wave * 16 + quad * 4 + r;
      xs[d][tl] = f2bf(acc[nt][r]);
    }
  }
  __syncthreads();
  const int bb = blockIdx.x >> 5;         // batch (32 tiles per batch)
  const int t0 = (blockIdx.x & 31) * 64;  // token offset in batch
#pragma unroll
  for (int it = 0; it < 2; ++it) {
    int i = tid + it * 256;
    int d = i >> 3, cc = (i & 7) * 8;
    float4 v = *(const float4*)&xs[d][cc];
    *(float4*)(vo + ((long)(bb * 64 + d)) * 2048 + t0 + cc) = v;
  }
}

// ---------------- kernel 2: causal flash attention ----------------
__device__ __forceinline__ void stage_loads(const unsigned short* kb, const unsigned short* vb,
                                            int kt, int tid, float4 kv[2], float4 vv[2]) {
  const float4* kg = (const float4*)(kb + (long)kt * 64 * 64);
#pragma unroll
  for (int it = 0; it < 2; ++it) {
    int i = tid + it * 256;
    kv[it] = kg[i];
    int d = i >> 3, cc = (i & 7) * 8;
    vv[it] = *(const float4*)(vb + (long)d * 2048 + kt * 64 + cc);
  }
}
__device__ __forceinline__ void stage_stores(unsigned short ksh[64][PITCH],
                                             unsigned short vsh[64][PITCH], int tid,
                                             const float4 kv[2], const float4 vv[2]) {
#pragma unroll
  for (int it = 0; it < 2; ++it) {
    int i = tid + it * 256;
    int d = i >> 3, cc = (i & 7) * 8;
    *(float4*)&ksh[d][cc] = kv[it];
    *(float4*)&vsh[d][cc] = vv[it];
  }
}

__global__ __launch_bounds__(256) void attn_kernel(
    const unsigned short* __restrict__ qg, const unsigned short* __restrict__ kg,
    const unsigned short* __restrict__ vg, float* __restrict__ out) {
  __shared__ unsigned short ks[2][64][PITCH];  // [buf][key][d]
  __shared__ unsigned short vs[2][64][PITCH];  // [buf][d][key]  (v^T)
  __shared__ unsigned short ps[4][16][PITCH];  // wave-private P [qrow][key]

  const int tid = threadIdx.x;
  const int lane = tid & 63, wave = tid >> 6;
  const int lo = lane & 15, quad = lane >> 4;
  const int b = blockIdx.x >> 4;
  const int pair = blockIdx.x & 15;
  const float Cs = 0.18033688011112042f;  // 0.125 * log2(e)

  const long boff = (long)b * 2048 * 64;
  const unsigned short* qb = qg + boff;
  const unsigned short* kb = kg + boff;
  const unsigned short* vb = vg + boff;  // [64][2048]
  float* ob = out + boff;

  for (int half = 0; half < 2; ++half) {
    const int qt = (half == 0) ? pair : 31 - pair;
    // Q fragments (A-operand), kept in registers for the whole tile
    bf16x8 aq[2];
    {
      const unsigned short* qr = qb + ((long)(qt * 64 + wave * 16 + lo)) * 64 + quad * 8;
      aq[0] = *(const bf16x8*)(qr);
      aq[1] = *(const bf16x8*)(qr + 32);
    }
    f32x4 oacc[4];
#pragma unroll
    for (int dt = 0; dt < 4; ++dt) oacc[dt] = (f32x4){0.f, 0.f, 0.f, 0.f};
    float m[4], l[4];
#pragma unroll
    for (int r = 0; r < 4; ++r) { m[r] = NEG_INF; l[r] = 0.f; }

    float4 kv[2], vv[2];
    stage_loads(kb, vb, qt * 0, tid, kv, vv);  // kt = 0
    stage_stores(ks[0], vs[0], tid, kv, vv);
    __syncthreads();

    for (int kt = 0; kt <= qt; ++kt) {
      const int buf = kt & 1;
      if (kt < qt) stage_loads(kb, vb, kt + 1, tid, kv, vv);  // prefetch next tile

      // S = Q K^T  (per wave: 16 q-rows x 64 keys)
      f32x4 s[4];
#pragma unroll
      for (int t = 0; t < 4; ++t) s[t] = (f32x4){0.f, 0.f, 0.f, 0.f};
#pragma unroll
      for (int kk = 0; kk < 2; ++kk) {
#pragma unroll
        for (int t = 0; t < 4; ++t) {
          bf16x8 bk = *(const bf16x8*)&ks[buf][t * 16 + lo][kk * 32 + quad * 8];
          s[t] = mfma16(aq[kk], bk, s[t]);
        }
      }
      // causal mask on the diagonal tile (tril keeps key <= q)
      if (kt == qt) {
#pragma unroll
        for (int t = 0; t < 4; ++t)
#pragma unroll
          for (int r = 0; r < 4; ++r) {
            int key = t * 16 + lo;
            int qrow = wave * 16 + quad * 4 + r;
            if (key > qrow) s[t][r] = NEG_INF;
          }
      }
      // online softmax (raw logits; scale folded into exp2 constant)
#pragma unroll
      for (int r = 0; r < 4; ++r) {
        float mx = fmaxf(fmaxf(s[0][r], s[1][r]), fmaxf(s[2][r], s[3][r]));
#pragma unroll
        for (int off = 1; off < 16; off <<= 1) mx = fmaxf(mx, __shfl_xor(mx, off, 64));
        float mnew = fmaxf(m[r], mx);
        float alpha = exp2f((m[r] - mnew) * Cs);
        m[r] = mnew;
        float psum = 0.f;
#pragma unroll
        for (int t = 0; t < 4; ++t) {
          float p = exp2f((s[t][r] - mnew) * Cs);
          s[t][r] = p;
          psum += p;
        }
        l[r] = l[r] * alpha + psum;
#pragma unroll
        for (int dt = 0; dt < 4; ++dt) oacc[dt][r] *= alpha;
      }
      // P -> wave-private LDS (C-layout -> A-layout transform)
#pragma unroll
      for (int t = 0; t < 4; ++t)
#pragma unroll
        for (int r = 0; r < 4; ++r)
          ps[wave][quad * 4 + r][t * 16 + lo] = f2bf(s[t][r]);
      asm volatile("s_waitcnt lgkmcnt(0)" ::: "memory");
      // O += P V
#pragma unroll
      for (int kk = 0; kk < 2; ++kk) {
        bf16x8 ap = *(const bf16x8*)&ps[wave][lo][kk * 32 + quad * 8];
#pragma unroll
        for (int dt = 0; dt < 4; ++dt) {
          bf16x8 bv = *(const bf16x8*)&vs[buf][dt * 16 + lo][kk * 32 + quad * 8];
          oacc[dt] = mfma16(ap, bv, oacc[dt]);
        }
      }
      if (kt < qt) stage_stores(ks[buf ^ 1], vs[buf ^ 1], tid, kv, vv);
      __syncthreads();
    }
    // epilogue: reduce l across the 16-lane column groups, normalize, store fp32
#pragma unroll
    for (int r = 0; r < 4; ++r) {
      float ls = l[r];
#pragma unroll
      for (int off = 1; off < 16; off <<= 1) ls += __shfl_xor(ls, off, 64);
      float inv = 1.0f / ls;
      float* orow = ob + (long)(qt * 64 + wave * 16 + quad * 4 + r) * 64;
#pragma unroll
      for (int dt = 0; dt < 4; ++dt) orow[dt * 16 + lo] = oacc[dt][r] * inv;
    }
  }
}

// ---------------- launcher ----------------
extern "C" void kernel_launch(void* const* d_in, const int* in_sizes, int n_in,
                              void* d_out, int out_size, void* d_ws, size_t ws_size,
                              hipStream_t stream) {
  const float* x = (const float*)d_in[0];
  const float* wq = (const float*)d_in[1];
  const float* wk = (const float*)d_in[2];
  const float* wv = (const float*)d_in[3];
  float* out = (float*)d_out;

  char* ws = (char*)d_ws;
  unsigned short* wt = (unsigned short*)ws;  // 192*384*2 = 147456 B
  const size_t qkv_elems = (size_t)16 * 2048 * 64;
  unsigned short* qws = (unsigned short*)(ws + 147456);
  unsigned short* kws = qws + qkv_elems;
  unsigned short* vws = kws + qkv_elems;

  prep_w<<<96, 256, 0, stream>>>(wq, wk, wv, wt);
  proj_kernel<<<512, 256, 0, stream>>>(x, wt, qws, kws, vws);
  attn_kernel<<<256, 256, 0, stream>>>(qws, kws, vws, out);
}